// Round 1
// baseline (119.409 us; speedup 1.0000x reference)
//
#include <hip/hip_runtime.h>
#include <math.h>

#define Bd   4
#define Td   4
#define Cd   32
#define Nd   16384
#define Fd   64
#define Kd   9
#define PADd 4
#define NT   128
#define NROWS (NT + 2*PADd)   // 136
#define XP    40              // ushorts per transposed row: 32 c + 8 pad; 80 B pitch (16B-aligned)
#define EPIT  36              // epilogue pitch (dwords)

typedef __attribute__((ext_vector_type(8))) _Float16 half8;   // MFMA A/B frag (4 VGPRs)
typedef __attribute__((ext_vector_type(4))) float    float4v; // MFMA acc frag
typedef __attribute__((ext_vector_type(4))) float    f32x4;   // NT-store friendly

#define A_WS_BYTES ((size_t)Td * Kd * 4 * 64 * 8 * 2)  // 147456

// LDS layout (bytes):
//   staging: xt [0,10880) | wlp [10880,15488) | cs [15488,17120)
//   epilogue: epi [0,18432) per-wave 4608 B (reused after barrier)
#define SM_XT  0
#define SM_WL  10880
#define SM_CS  15488
#define SM_BYTES 18432

union FragU { uint4 u; half8 h; };

__device__ __forceinline__ float sigma_as_float(const void* p) {
    int iv = *(const int*)p;
    if (iv > 0 && iv < 1000000) return (float)iv;
    return __int_as_float(iv);
}

__device__ __forceinline__ unsigned short f32_to_f16_bits(float f) {
    _Float16 h = (_Float16)f;           // v_cvt_f16_f32, RNE
    return *reinterpret_cast<unsigned short*>(&h);
}

__device__ __forceinline__ unsigned int pack_f16x2(float a, float b) {
    unsigned int lo = f32_to_f16_bits(a);
    unsigned int hi = f32_to_f16_bits(b);
    return lo | (hi << 16);             // cvt,cvt,pack — RNE both halves
}

// ---- prep: weight fp32 [T][F][C][K] -> fp16 A-fragments in ws (u32-vectorized) ----
// u16 layout unchanged: u16idx = (((t*K + k)*4 + ft)*64 + lane)*8 + j ;
// val = W[t][ft*16+(lane&15)][(lane>>4)*8+j][k].  Here idx runs over j-PAIRS (u32).
__global__ void prep_weights(const float* __restrict__ w, unsigned int* __restrict__ a) {
    int idx = blockIdx.x * 256 + threadIdx.x;
    if (idx >= Td * Kd * 4 * 64 * 4) return;          // 36864 u32
    int jp   = idx & 3;            // j = 2*jp, 2*jp+1
    int lane = (idx >> 2) & 63;
    int ft   = (idx >> 8) & 3;
    int tk   = idx >> 10;          // t*Kd + k
    int k    = tk % Kd;
    int t    = tk / Kd;
    int m = lane & 15, q = lane >> 4;
    int f = ft * 16 + m;
    int c = q * 8 + jp * 2;
    const float* wp = w + (((size_t)t * Fd + f) * Cd + c) * Kd + k;
    float v0 = wp[0];
    float v1 = wp[Kd];             // c+1, same k
    a[idx] = pack_f16x2(v0, v1);
}

__global__ __launch_bounds__(256, 4)
void swconv_mfma4(const float* __restrict__ x,
                  const float* __restrict__ coords,
                  const unsigned short* __restrict__ aw,
                  const void* __restrict__ sigma_p,
                  float* __restrict__ out)
{
    __shared__ __align__(16) unsigned char smem[SM_BYTES];
    unsigned int (*wlp)[NT]  = (unsigned int (*)[NT])(smem + SM_WL);    // packed (h,h) per (k, n_local)
    float (*cs)[NROWS]       = (float (*)[NROWS])(smem + SM_CS);

    const int tid  = threadIdx.x;
    const int lane = tid & 63;
    const int wv   = tid >> 6;          // wave 0..3, owns n_local [32*wv, 32*wv+32)
    const int tile = blockIdx.x, t = blockIdx.y, b = blockIdx.z;
    const int n0   = tile * NT;
    const float inv_sigma = 1.0f / sigma_as_float(sigma_p);

    // ---- stage x -> fp16 TRANSPOSED + XOR-swizzled xt ----
    // Per lane: 4 channel-strided dword loads (wave reads 256B contiguous per instr),
    // pack 4 halfs, ONE ds_write_b64 into chunk (cg>>1)^((r>>3)&3).
    // Old path was 4x ds_write_b16 at bank (20r + c/2) % 32 with r=4rq -> ~17-way conflict.
    const float* xbt = x + (size_t)(b * Td + t) * Cd * Nd;
    #pragma unroll
    for (int half = 0; half < 2; ++half) {
        const int cg = wv * 2 + half;               // c-group 0..7 (4 channels)
        const float* xc = xbt + (size_t)(cg * 4) * Nd;
        #pragma unroll
        for (int rr = 0; rr < 3; ++rr) {
            int r = rr * 64 + lane;
            if (r < NROWS) {
                int n = n0 - PADd + r;
                float v0 = 0.f, v1 = 0.f, v2 = 0.f, v3 = 0.f;
                if (n >= 0 && n < Nd) {
                    v0 = xc[n];
                    v1 = xc[n + Nd];
                    v2 = xc[n + 2 * Nd];
                    v3 = xc[n + 3 * Nd];
                }
                unsigned int p0 = pack_f16x2(v0, v1);
                unsigned int p1 = pack_f16x2(v2, v3);
                int chunk = (cg >> 1) ^ ((r >> 3) & 3);         // 16-B granular swizzle
                unsigned char* dst = smem + SM_XT + (size_t)r * (XP * 2)
                                   + chunk * 16 + (cg & 1) * 8;
                *reinterpret_cast<uint2*>(dst) = make_uint2(p0, p1);
            }
        }
    }

    // ---- stage coords (coalesced) ----
    const float* cbt = coords + (size_t)(b * Td + t) * 3 * Nd;
    for (int i = tid; i < 3 * NROWS; i += 256) {
        int c = i / NROWS, r = i - c * NROWS;
        int n = n0 - PADd + r;
        cs[c][r] = (n >= 0 && n < Nd) ? cbt[(size_t)c * Nd + n] : 0.0f;
    }

    // ---- A-fragment prefetch k=0 (L2-hot, independent of LDS) ----
    const int m = lane & 15, q = lane >> 4;
    const unsigned short* Abase = aw + (size_t)t * Kd * 4 * 64 * 8 + (size_t)lane * 8;
    FragU afr[2][4];
    #pragma unroll
    for (int ft = 0; ft < 4; ++ft)
        afr[0][ft].u = *reinterpret_cast<const uint4*>(Abase + (size_t)ft * 512);

    __syncthreads();

    // ---- distance weights (wave-private: write & read by same wave) ----
    {
        int nl   = wv * 32 + (lane & 31);
        int hf   = lane >> 5;               // k 0..4 / 5..8
        int il   = nl + PADd;
        float c0 = cs[0][il], c1 = cs[1][il], c2 = cs[2][il];
        int k0 = hf ? 5 : 0, k1 = hf ? Kd : 5;
        #pragma unroll
        for (int k = k0; k < k1; ++k) {
            float d0 = cs[0][nl + k] - c0;
            float d1 = cs[1][nl + k] - c1;
            float d2 = cs[2][nl + k] - c2;
            float s = d0 * d0 + d1 * d1 + d2 * d2;
            float d = (s > 0.0f) ? sqrtf(s) : 0.0f;
            float w = fmaxf(1.0f - d * inv_sigma, 0.0f);
            wlp[k][nl] = (unsigned int)f32_to_f16_bits(w) * 0x00010001u;  // (h,h)
        }
    }

    float4v acc[4][2];
    #pragma unroll
    for (int ft = 0; ft < 4; ++ft)
        #pragma unroll
        for (int nt = 0; nt < 2; ++nt)
            acc[ft][nt] = (float4v){0.f, 0.f, 0.f, 0.f};

    for (int k = 0; k < Kd; ++k) {
        const int cur = k & 1;
        if (k + 1 < Kd) {
            #pragma unroll
            for (int ft = 0; ft < 4; ++ft)
                afr[cur ^ 1][ft].u = *reinterpret_cast<const uint4*>(Abase + (size_t)((k + 1) * 4 + ft) * 512);
        }
        #pragma unroll
        for (int nt = 0; nt < 2; ++nt) {
            const int ncol = wv * 32 + nt * 16 + m;   // n_local of this lane's column
            const int r    = ncol + k;                // xt row (tap nn = n + k - 4)
            const int ch   = q ^ ((r >> 3) & 3);      // match staging swizzle
            FragU xv;
            xv.u = *reinterpret_cast<const uint4*>(smem + SM_XT + (size_t)r * (XP * 2) + ch * 16);
            unsigned int wp = wlp[k][ncol];
            FragU ww; ww.u = make_uint4(wp, wp, wp, wp);
            half8 bfr = xv.h * ww.h;                  // 4x v_pk_mul_f16
            #pragma unroll
            for (int ft = 0; ft < 4; ++ft)
                acc[ft][nt] = __builtin_amdgcn_mfma_f32_16x16x32_f16(afr[cur][ft].h, bfr, acc[ft][nt], 0, 0, 0);
        }
    }

    // ---- epilogue: LDS transpose -> full-line float4 NT stores ----
    __syncthreads();   // xt/wlp dead for everyone before epi overwrite
    float (*epi)[EPIT] = (float (*)[EPIT])(smem + (size_t)wv * 32 * EPIT * 4);  // per-wave [32][36]

    float* ob = out + (size_t)(b * Td + t) * Fd * Nd + n0 + wv * 32;
    #pragma unroll
    for (int fc = 0; fc < 2; ++fc) {          // f chunks [0,32) / [32,64)
        #pragma unroll
        for (int ft2 = 0; ft2 < 2; ++ft2) {
            const int ft = fc * 2 + ft2;
            #pragma unroll
            for (int nt = 0; nt < 2; ++nt) {
                const int np = nt * 16 + m;
                #pragma unroll
                for (int rr = 0; rr < 4; ++rr)
                    epi[ft2 * 16 + q * 4 + rr][np] = acc[ft][nt][rr];
            }
        }
        #pragma unroll
        for (int inst = 0; inst < 4; ++inst) {
            const int fl = inst * 8 + (lane >> 3);
            const int np = (lane & 7) * 4;
            f32x4 v = *reinterpret_cast<const f32x4*>(&epi[fl][np]);
            // write-once stream: NT store keeps L2 for the hot A-fragment table
            __builtin_nontemporal_store(v, reinterpret_cast<f32x4*>(ob + (size_t)(fc * 32 + fl) * Nd + np));
        }
    }
}

// ---- fallback fp32 kernel (ws too small) ----
__global__ __launch_bounds__(256, 4)
void swconv_f32_kernel(const float* __restrict__ x,
                       const float* __restrict__ coords,
                       const float* __restrict__ weight,
                       const void*  __restrict__ sigma_p,
                       float* __restrict__ out)
{
    __shared__ float xsf[Cd][NROWS + 1];
    __shared__ float csf[3][NROWS + 1];
    const int tid = threadIdx.x;
    const int tile = blockIdx.x, t = blockIdx.y, b = blockIdx.z;
    const int n0 = tile * NT;
    const float inv_sigma = 1.0f / sigma_as_float(sigma_p);

    const float* xbt = x + (size_t)(b * Td + t) * Cd * Nd;
    for (int idx = tid; idx < Cd * NROWS; idx += 256) {
        int c = idx / NROWS, i = idx - c * NROWS, n = n0 - PADd + i;
        xsf[c][i] = (n >= 0 && n < Nd) ? xbt[(size_t)c * Nd + n] : 0.0f;
    }
    const float* cbt = coords + (size_t)(b * Td + t) * 3 * Nd;
    for (int idx = tid; idx < 3 * NROWS; idx += 256) {
        int c = idx / NROWS, i = idx - c * NROWS, n = n0 - PADd + i;
        csf[c][i] = (n >= 0 && n < Nd) ? cbt[(size_t)c * Nd + n] : 0.0f;
    }
    __syncthreads();
    if (tid >= NT) return;

    float wk[Kd];
    {
        const float c0 = csf[0][tid + PADd], c1 = csf[1][tid + PADd], c2 = csf[2][tid + PADd];
        #pragma unroll
        for (int k = 0; k < Kd; ++k) {
            float d0 = csf[0][tid + k] - c0, d1 = csf[1][tid + k] - c1, d2 = csf[2][tid + k] - c2;
            float s = d0 * d0 + d1 * d1 + d2 * d2;
            float d = (s > 0.0f) ? sqrtf(s) : 0.0f;
            wk[k] = fmaxf(1.0f - d * inv_sigma, 0.0f);
        }
    }
    float accf[Fd];
    #pragma unroll
    for (int f = 0; f < Fd; ++f) accf[f] = 0.0f;
    const float* wt = weight + (size_t)t * Fd * Cd * Kd;
    for (int c = 0; c < Cd; ++c) {
        float xv[Kd];
        #pragma unroll
        for (int k = 0; k < Kd; ++k) xv[k] = xsf[c][tid + k];
        const float* wp = wt + c * Kd;
        #pragma unroll
        for (int k = 0; k < Kd; ++k) {
            float v = xv[k] * wk[k];
            #pragma unroll
            for (int f = 0; f < Fd; ++f)
                accf[f] = fmaf(v, wp[(size_t)f * Cd * Kd + k], accf[f]);
        }
    }
    float* op = out + (size_t)(b * Td + t) * Fd * Nd + n0 + tid;
    #pragma unroll
    for (int f = 0; f < Fd; ++f) op[(size_t)f * Nd] = accf[f];
}

extern "C" void kernel_launch(void* const* d_in, const int* in_sizes, int n_in,
                              void* d_out, int out_size, void* d_ws, size_t ws_size,
                              hipStream_t stream) {
    const float* x      = (const float*)d_in[0];
    const float* coords = (const float*)d_in[1];
    const float* weight = (const float*)d_in[2];
    const void*  sigma  = d_in[3];
    float* out = (float*)d_out;

    if (ws_size >= A_WS_BYTES) {
        unsigned int* aw = (unsigned int*)d_ws;
        prep_weights<<<(Td * Kd * 4 * 64 * 4 + 255) / 256, 256, 0, stream>>>(weight, aw);
        dim3 grid(Nd / NT, Td, Bd);   // 2048 blocks
        swconv_mfma4<<<grid, dim3(256), 0, stream>>>(x, coords, (const unsigned short*)aw, sigma, out);
    } else {
        dim3 grid(Nd / NT, Td, Bd);
        swconv_f32_kernel<<<grid, dim3(256), 0, stream>>>(x, coords, weight, sigma, out);
    }
}

// Round 2
// 114.876 us; speedup vs baseline: 1.0395x; 1.0395x over previous
//
#include <hip/hip_runtime.h>
#include <math.h>

#define Bd   4
#define Td   4
#define Cd   32
#define Nd   16384
#define Fd   64
#define Kd   9
#define PADd 4
#define NT   128
#define NROWS (NT + 2*PADd)   // 136
#define XP    40              // ushorts per transposed row: 32 c + 8 pad; 80 B pitch (16B-aligned)
#define EPIT  36              // epilogue pitch (dwords)

typedef __attribute__((ext_vector_type(8))) _Float16 half8;   // MFMA A/B frag (4 VGPRs)
typedef __attribute__((ext_vector_type(4))) float    float4v; // MFMA acc frag

#define A_WS_BYTES ((size_t)Td * Kd * 4 * 64 * 8 * 2)  // 147456

// LDS layout (bytes):
//   staging: xt [0,10880) | wlp [10880,15488) | cs [15488,17120)
//   epilogue: epi [0,18432) per-wave 4608 B (reused after barrier)
#define SM_XT  0
#define SM_WL  10880
#define SM_CS  15488
#define SM_BYTES 18432

union FragU { uint4 u; half8 h; };

__device__ __forceinline__ float sigma_as_float(const void* p) {
    int iv = *(const int*)p;
    if (iv > 0 && iv < 1000000) return (float)iv;
    return __int_as_float(iv);
}

__device__ __forceinline__ unsigned short f32_to_f16_bits(float f) {
    _Float16 h = (_Float16)f;           // v_cvt_f16_f32, RNE
    return *reinterpret_cast<unsigned short*>(&h);
}

__device__ __forceinline__ unsigned int pack_f16x2(float a, float b) {
    unsigned int lo = f32_to_f16_bits(a);
    unsigned int hi = f32_to_f16_bits(b);
    return lo | (hi << 16);             // cvt,cvt,pack — RNE both halves
}

// ---- prep: weight fp32 [T][F][C][K] -> fp16 A-fragments in ws (u32-vectorized) ----
// u16 layout unchanged: u16idx = (((t*K + k)*4 + ft)*64 + lane)*8 + j ;
// val = W[t][ft*16+(lane&15)][(lane>>4)*8+j][k].  Here idx runs over j-PAIRS (u32).
__global__ void prep_weights(const float* __restrict__ w, unsigned int* __restrict__ a) {
    int idx = blockIdx.x * 256 + threadIdx.x;
    if (idx >= Td * Kd * 4 * 64 * 4) return;          // 36864 u32
    int jp   = idx & 3;            // j = 2*jp, 2*jp+1
    int lane = (idx >> 2) & 63;
    int ft   = (idx >> 8) & 3;
    int tk   = idx >> 10;          // t*Kd + k
    int k    = tk % Kd;
    int t    = tk / Kd;
    int m = lane & 15, q = lane >> 4;
    int f = ft * 16 + m;
    int c = q * 8 + jp * 2;
    const float* wp = w + (((size_t)t * Fd + f) * Cd + c) * Kd + k;
    float v0 = wp[0];
    float v1 = wp[Kd];             // c+1, same k
    a[idx] = pack_f16x2(v0, v1);
}

__global__ __launch_bounds__(256, 4)
void swconv_mfma4(const float* __restrict__ x,
                  const float* __restrict__ coords,
                  const unsigned short* __restrict__ aw,
                  const void* __restrict__ sigma_p,
                  float* __restrict__ out)
{
    __shared__ __align__(16) unsigned char smem[SM_BYTES];
    unsigned int (*wlp)[NT]  = (unsigned int (*)[NT])(smem + SM_WL);    // packed (h,h) per (k, n_local)
    float (*cs)[NROWS]       = (float (*)[NROWS])(smem + SM_CS);

    const int tid  = threadIdx.x;
    const int lane = tid & 63;
    const int wv   = tid >> 6;          // wave 0..3, owns n_local [32*wv, 32*wv+32)
    const int tile = blockIdx.x, t = blockIdx.y, b = blockIdx.z;
    const int n0   = tile * NT;
    const float inv_sigma = 1.0f / sigma_as_float(sigma_p);

    // ---- stage x -> fp16 TRANSPOSED + XOR-swizzled xt ----
    // Per lane: 4 channel-strided dword loads (wave reads 256B contiguous per instr),
    // pack 4 halfs, ONE ds_write_b64 into chunk (cg>>1)^((r>>3)&3).
    // (Old path was 4x ds_write_b16 at ~17-way conflict.)
    const float* xbt = x + (size_t)(b * Td + t) * Cd * Nd;
    #pragma unroll
    for (int half = 0; half < 2; ++half) {
        const int cg = wv * 2 + half;               // c-group 0..7 (4 channels)
        const float* xc = xbt + (size_t)(cg * 4) * Nd;
        #pragma unroll
        for (int rr = 0; rr < 3; ++rr) {
            int r = rr * 64 + lane;
            if (r < NROWS) {
                int n = n0 - PADd + r;
                float v0 = 0.f, v1 = 0.f, v2 = 0.f, v3 = 0.f;
                if (n >= 0 && n < Nd) {
                    v0 = xc[n];
                    v1 = xc[n + Nd];
                    v2 = xc[n + 2 * Nd];
                    v3 = xc[n + 3 * Nd];
                }
                unsigned int p0 = pack_f16x2(v0, v1);
                unsigned int p1 = pack_f16x2(v2, v3);
                int chunk = (cg >> 1) ^ ((r >> 3) & 3);         // 16-B granular swizzle
                unsigned char* dst = smem + SM_XT + (size_t)r * (XP * 2)
                                   + chunk * 16 + (cg & 1) * 8;
                *reinterpret_cast<uint2*>(dst) = make_uint2(p0, p1);
            }
        }
    }

    // ---- stage coords (coalesced) ----
    const float* cbt = coords + (size_t)(b * Td + t) * 3 * Nd;
    for (int i = tid; i < 3 * NROWS; i += 256) {
        int c = i / NROWS, r = i - c * NROWS;
        int n = n0 - PADd + r;
        cs[c][r] = (n >= 0 && n < Nd) ? cbt[(size_t)c * Nd + n] : 0.0f;
    }

    // ---- A-fragment prefetch k=0 (L2-hot, independent of LDS) ----
    const int m = lane & 15, q = lane >> 4;
    const unsigned short* Abase = aw + (size_t)t * Kd * 4 * 64 * 8 + (size_t)lane * 8;
    FragU afr[2][4];
    #pragma unroll
    for (int ft = 0; ft < 4; ++ft)
        afr[0][ft].u = *reinterpret_cast<const uint4*>(Abase + (size_t)ft * 512);

    __syncthreads();

    // ---- distance weights (wave-private: write & read by same wave) ----
    {
        int nl   = wv * 32 + (lane & 31);
        int hf   = lane >> 5;               // k 0..4 / 5..8
        int il   = nl + PADd;
        float c0 = cs[0][il], c1 = cs[1][il], c2 = cs[2][il];
        int k0 = hf ? 5 : 0, k1 = hf ? Kd : 5;
        #pragma unroll
        for (int k = k0; k < k1; ++k) {
            float d0 = cs[0][nl + k] - c0;
            float d1 = cs[1][nl + k] - c1;
            float d2 = cs[2][nl + k] - c2;
            float s = d0 * d0 + d1 * d1 + d2 * d2;
            float d = (s > 0.0f) ? sqrtf(s) : 0.0f;
            float w = fmaxf(1.0f - d * inv_sigma, 0.0f);
            wlp[k][nl] = (unsigned int)f32_to_f16_bits(w) * 0x00010001u;  // (h,h)
        }
    }

    float4v acc[4][2];
    #pragma unroll
    for (int ft = 0; ft < 4; ++ft)
        #pragma unroll
        for (int nt = 0; nt < 2; ++nt)
            acc[ft][nt] = (float4v){0.f, 0.f, 0.f, 0.f};

    for (int k = 0; k < Kd; ++k) {
        const int cur = k & 1;
        if (k + 1 < Kd) {
            #pragma unroll
            for (int ft = 0; ft < 4; ++ft)
                afr[cur ^ 1][ft].u = *reinterpret_cast<const uint4*>(Abase + (size_t)((k + 1) * 4 + ft) * 512);
        }
        #pragma unroll
        for (int nt = 0; nt < 2; ++nt) {
            const int ncol = wv * 32 + nt * 16 + m;   // n_local of this lane's column
            const int r    = ncol + k;                // xt row (tap nn = n + k - 4)
            const int ch   = q ^ ((r >> 3) & 3);      // match staging swizzle
            FragU xv;
            xv.u = *reinterpret_cast<const uint4*>(smem + SM_XT + (size_t)r * (XP * 2) + ch * 16);
            unsigned int wp = wlp[k][ncol];
            FragU ww; ww.u = make_uint4(wp, wp, wp, wp);
            half8 bfr = xv.h * ww.h;                  // 4x v_pk_mul_f16
            #pragma unroll
            for (int ft = 0; ft < 4; ++ft)
                acc[ft][nt] = __builtin_amdgcn_mfma_f32_16x16x32_f16(afr[cur][ft].h, bfr, acc[ft][nt], 0, 0, 0);
        }
    }

    // ---- epilogue: LDS transpose -> full-line float4 stores ----
    // NOTE R2: NT stores REVERTED — out (64 MB) fits Infinity Cache; nt forced
    // synchronous HBM writes inside the kernel (~8 µs regression mechanism).
    __syncthreads();   // xt/wlp dead for everyone before epi overwrite
    float (*epi)[EPIT] = (float (*)[EPIT])(smem + (size_t)wv * 32 * EPIT * 4);  // per-wave [32][36]

    float* ob = out + (size_t)(b * Td + t) * Fd * Nd + n0 + wv * 32;
    #pragma unroll
    for (int fc = 0; fc < 2; ++fc) {          // f chunks [0,32) / [32,64)
        #pragma unroll
        for (int ft2 = 0; ft2 < 2; ++ft2) {
            const int ft = fc * 2 + ft2;
            #pragma unroll
            for (int nt = 0; nt < 2; ++nt) {
                const int np = nt * 16 + m;
                #pragma unroll
                for (int rr = 0; rr < 4; ++rr)
                    epi[ft2 * 16 + q * 4 + rr][np] = acc[ft][nt][rr];
            }
        }
        #pragma unroll
        for (int inst = 0; inst < 4; ++inst) {
            const int fl = inst * 8 + (lane >> 3);
            const int np = (lane & 7) * 4;
            float4 v = *reinterpret_cast<const float4*>(&epi[fl][np]);
            *reinterpret_cast<float4*>(ob + (size_t)(fc * 32 + fl) * Nd + np) = v;
        }
    }
}

// ---- fallback fp32 kernel (ws too small) ----
__global__ __launch_bounds__(256, 4)
void swconv_f32_kernel(const float* __restrict__ x,
                       const float* __restrict__ coords,
                       const float* __restrict__ weight,
                       const void*  __restrict__ sigma_p,
                       float* __restrict__ out)
{
    __shared__ float xsf[Cd][NROWS + 1];
    __shared__ float csf[3][NROWS + 1];
    const int tid = threadIdx.x;
    const int tile = blockIdx.x, t = blockIdx.y, b = blockIdx.z;
    const int n0 = tile * NT;
    const float inv_sigma = 1.0f / sigma_as_float(sigma_p);

    const float* xbt = x + (size_t)(b * Td + t) * Cd * Nd;
    for (int idx = tid; idx < Cd * NROWS; idx += 256) {
        int c = idx / NROWS, i = idx - c * NROWS, n = n0 - PADd + i;
        xsf[c][i] = (n >= 0 && n < Nd) ? xbt[(size_t)c * Nd + n] : 0.0f;
    }
    const float* cbt = coords + (size_t)(b * Td + t) * 3 * Nd;
    for (int idx = tid; idx < 3 * NROWS; idx += 256) {
        int c = idx / NROWS, i = idx - c * NROWS, n = n0 - PADd + i;
        csf[c][i] = (n >= 0 && n < Nd) ? cbt[(size_t)c * Nd + n] : 0.0f;
    }
    __syncthreads();
    if (tid >= NT) return;

    float wk[Kd];
    {
        const float c0 = csf[0][tid + PADd], c1 = csf[1][tid + PADd], c2 = csf[2][tid + PADd];
        #pragma unroll
        for (int k = 0; k < Kd; ++k) {
            float d0 = csf[0][tid + k] - c0, d1 = csf[1][tid + k] - c1, d2 = csf[2][tid + k] - c2;
            float s = d0 * d0 + d1 * d1 + d2 * d2;
            float d = (s > 0.0f) ? sqrtf(s) : 0.0f;
            wk[k] = fmaxf(1.0f - d * inv_sigma, 0.0f);
        }
    }
    float accf[Fd];
    #pragma unroll
    for (int f = 0; f < Fd; ++f) accf[f] = 0.0f;
    const float* wt = weight + (size_t)t * Fd * Cd * Kd;
    for (int c = 0; c < Cd; ++c) {
        float xv[Kd];
        #pragma unroll
        for (int k = 0; k < Kd; ++k) xv[k] = xsf[c][tid + k];
        const float* wp = wt + c * Kd;
        #pragma unroll
        for (int k = 0; k < Kd; ++k) {
            float v = xv[k] * wk[k];
            #pragma unroll
            for (int f = 0; f < Fd; ++f)
                accf[f] = fmaf(v, wp[(size_t)f * Cd * Kd + k], accf[f]);
        }
    }
    float* op = out + (size_t)(b * Td + t) * Fd * Nd + n0 + tid;
    #pragma unroll
    for (int f = 0; f < Fd; ++f) op[(size_t)f * Nd] = accf[f];
}

extern "C" void kernel_launch(void* const* d_in, const int* in_sizes, int n_in,
                              void* d_out, int out_size, void* d_ws, size_t ws_size,
                              hipStream_t stream) {
    const float* x      = (const float*)d_in[0];
    const float* coords = (const float*)d_in[1];
    const float* weight = (const float*)d_in[2];
    const void*  sigma  = d_in[3];
    float* out = (float*)d_out;

    if (ws_size >= A_WS_BYTES) {
        unsigned int* aw = (unsigned int*)d_ws;
        prep_weights<<<(Td * Kd * 4 * 64 * 4 + 255) / 256, 256, 0, stream>>>(weight, aw);
        dim3 grid(Nd / NT, Td, Bd);   // 2048 blocks
        swconv_mfma4<<<grid, dim3(256), 0, stream>>>(x, coords, (const unsigned short*)aw, sigma, out);
    } else {
        dim3 grid(Nd / NT, Td, Bd);
        swconv_f32_kernel<<<grid, dim3(256), 0, stream>>>(x, coords, weight, sigma, out);
    }
}

// Round 3
// 110.812 us; speedup vs baseline: 1.0776x; 1.0367x over previous
//
#include <hip/hip_runtime.h>
#include <math.h>

#define Bd   4
#define Td   4
#define Cd   32
#define Nd   16384
#define Fd   64
#define Kd   9
#define PADd 4
#define NT   128
#define NROWS (NT + 2*PADd)   // 136
#define NCHUNK (NROWS/4)      // 34 float4 chunks per channel row
#define XP    40              // ushorts per transposed row: 32 c + 8 pad; 80 B pitch (16B-aligned)
#define EPIT  36              // epilogue pitch (dwords)

typedef __attribute__((ext_vector_type(8))) _Float16 half8;   // MFMA A/B frag (4 VGPRs)
typedef __attribute__((ext_vector_type(4))) float    float4v; // MFMA acc frag

#define A_WS_BYTES ((size_t)Td * Kd * 4 * 64 * 8 * 2)  // 147456

// LDS layout (bytes):
//   staging: xt [0,10880) | wlp [10880,15488) | cs [15488,17120)
//   epilogue: epi [0,18432) per-wave 4608 B (reused after barrier)
#define SM_XT  0
#define SM_WL  10880
#define SM_CS  15488
#define SM_BYTES 18432

union FragU { uint4 u; half8 h; };

__device__ __forceinline__ float sigma_as_float(const void* p) {
    int iv = *(const int*)p;
    if (iv > 0 && iv < 1000000) return (float)iv;
    return __int_as_float(iv);
}

__device__ __forceinline__ unsigned short f32_to_f16_bits(float f) {
    _Float16 h = (_Float16)f;           // v_cvt_f16_f32, RNE
    return *reinterpret_cast<unsigned short*>(&h);
}

// ---- prep: weight fp32 [T][F][C][K] -> fp16 A-fragments in ws ----
// idx = (((t*K + k)*4 + ft)*64 + lane)*8 + j ; val = W[t][ft*16+(lane&15)][(lane>>4)*8+j][k]
// NOTE R3: reverted to R0's scalar form. The u32-pair variant (R1/R2) was part of
// a +3.7 µs kernel-side regression vs R0; single-variable revert to the proven config.
__global__ void prep_weights(const float* __restrict__ w, unsigned short* __restrict__ a) {
    int idx = blockIdx.x * 256 + threadIdx.x;
    if (idx >= Td * Kd * 4 * 64 * 8) return;
    int j    = idx & 7;
    int lane = (idx >> 3) & 63;
    int ft   = (idx >> 9) & 3;
    int k    = (idx >> 11) % Kd;
    int t    = idx / (Kd * 4 * 64 * 8);
    int m = lane & 15, q = lane >> 4;
    int f = ft * 16 + m;
    int c = q * 8 + j;
    float v = w[(((size_t)t * Fd + f) * Cd + c) * Kd + k];
    a[idx] = f32_to_f16_bits(v);
}

__global__ __launch_bounds__(256, 4)
void swconv_mfma4(const float* __restrict__ x,
                  const float* __restrict__ coords,
                  const unsigned short* __restrict__ aw,
                  const void* __restrict__ sigma_p,
                  float* __restrict__ out)
{
    __shared__ __align__(16) unsigned char smem[SM_BYTES];
    unsigned short (*xt)[XP] = (unsigned short (*)[XP])(smem + SM_XT);   // [NROWS][XP] fp16, transposed
    unsigned int (*wlp)[NT]  = (unsigned int (*)[NT])(smem + SM_WL);    // packed (h,h) per (k, n_local)
    float (*cs)[NROWS]       = (float (*)[NROWS])(smem + SM_CS);

    const int tid  = threadIdx.x;
    const int lane = tid & 63;
    const int wv   = tid >> 6;          // wave 0..3, owns n_local [32*wv, 32*wv+32)
    const int tile = blockIdx.x, t = blockIdx.y, b = blockIdx.z;
    const int n0   = tile * NT;
    const float inv_sigma = 1.0f / sigma_as_float(sigma_p);

    // ---- stage x -> fp16 TRANSPOSED xt[r][c] (float4 global loads) ----
    // NOTE R3: reverted to R0's float4-load + b16-write path. R1's strided-dword
    // rewrite (fixing an LDS write conflict that was NOT on the critical path)
    // cost ~3 µs of VMEM issue pressure at the kernel front edge — regime rule:
    // a conflict fix only pays when the LDS pipe is the critical path.
    const float* xbt = x + (size_t)(b * Td + t) * Cd * Nd;
    #pragma unroll 2
    for (int i = tid; i < Cd * NCHUNK; i += 256) {
        int c  = i / NCHUNK;
        int rq = i - c * NCHUNK;
        int nf = n0 - PADd + rq * 4;
        float4 v = make_float4(0.f, 0.f, 0.f, 0.f);
        if (nf >= 0 && nf < Nd)
            v = *reinterpret_cast<const float4*>(xbt + (size_t)c * Nd + nf);
        int r = rq * 4;
        xt[r + 0][c] = f32_to_f16_bits(v.x);
        xt[r + 1][c] = f32_to_f16_bits(v.y);
        xt[r + 2][c] = f32_to_f16_bits(v.z);
        xt[r + 3][c] = f32_to_f16_bits(v.w);
    }

    // ---- stage coords (coalesced) ----
    const float* cbt = coords + (size_t)(b * Td + t) * 3 * Nd;
    for (int i = tid; i < 3 * NROWS; i += 256) {
        int c = i / NROWS, r = i - c * NROWS;
        int n = n0 - PADd + r;
        cs[c][r] = (n >= 0 && n < Nd) ? cbt[(size_t)c * Nd + n] : 0.0f;
    }

    // ---- A-fragment prefetch k=0 (L2-hot, independent of LDS) ----
    const int m = lane & 15, q = lane >> 4;
    const unsigned short* Abase = aw + (size_t)t * Kd * 4 * 64 * 8 + (size_t)lane * 8;
    FragU afr[2][4];
    #pragma unroll
    for (int ft = 0; ft < 4; ++ft)
        afr[0][ft].u = *reinterpret_cast<const uint4*>(Abase + (size_t)ft * 512);

    __syncthreads();

    // ---- distance weights (wave-private: write & read by same wave) ----
    {
        int nl   = wv * 32 + (lane & 31);
        int half = lane >> 5;               // k 0..4 / 5..8
        int il   = nl + PADd;
        float c0 = cs[0][il], c1 = cs[1][il], c2 = cs[2][il];
        int k0 = half ? 5 : 0, k1 = half ? Kd : 5;
        #pragma unroll
        for (int k = k0; k < k1; ++k) {
            float d0 = cs[0][nl + k] - c0;
            float d1 = cs[1][nl + k] - c1;
            float d2 = cs[2][nl + k] - c2;
            float s = d0 * d0 + d1 * d1 + d2 * d2;
            float d = (s > 0.0f) ? sqrtf(s) : 0.0f;
            float w = fmaxf(1.0f - d * inv_sigma, 0.0f);
            wlp[k][nl] = (unsigned int)f32_to_f16_bits(w) * 0x00010001u;  // (h,h)
        }
    }

    float4v acc[4][2];
    #pragma unroll
    for (int ft = 0; ft < 4; ++ft)
        #pragma unroll
        for (int nt = 0; nt < 2; ++nt)
            acc[ft][nt] = (float4v){0.f, 0.f, 0.f, 0.f};

    for (int k = 0; k < Kd; ++k) {
        const int cur = k & 1;
        if (k + 1 < Kd) {
            #pragma unroll
            for (int ft = 0; ft < 4; ++ft)
                afr[cur ^ 1][ft].u = *reinterpret_cast<const uint4*>(Abase + (size_t)((k + 1) * 4 + ft) * 512);
        }
        #pragma unroll
        for (int nt = 0; nt < 2; ++nt) {
            const int ncol = wv * 32 + nt * 16 + m;   // n_local of this lane's column
            const int r    = ncol + k;                // xt row (tap nn = n + k - 4)
            FragU xv; xv.u = *reinterpret_cast<const uint4*>(&xt[r][q * 8]);  // 8 c's, one ds_read_b128
            unsigned int wp = wlp[k][ncol];
            FragU ww; ww.u = make_uint4(wp, wp, wp, wp);
            half8 bfr = xv.h * ww.h;                  // 4x v_pk_mul_f16
            #pragma unroll
            for (int ft = 0; ft < 4; ++ft)
                acc[ft][nt] = __builtin_amdgcn_mfma_f32_16x16x32_f16(afr[cur][ft].h, bfr, acc[ft][nt], 0, 0, 0);
        }
    }

    // ---- epilogue: LDS transpose -> full-line float4 stores ----
    // (plain cached stores: out is L3-resident; NT stores measured −4.5 µs worse in R1/R2 A/B)
    __syncthreads();   // xt/wlp dead for everyone before epi overwrite
    float (*epi)[EPIT] = (float (*)[EPIT])(smem + (size_t)wv * 32 * EPIT * 4);  // per-wave [32][36]

    float* ob = out + (size_t)(b * Td + t) * Fd * Nd + n0 + wv * 32;
    #pragma unroll
    for (int fc = 0; fc < 2; ++fc) {          // f chunks [0,32) / [32,64)
        #pragma unroll
        for (int ft2 = 0; ft2 < 2; ++ft2) {
            const int ft = fc * 2 + ft2;
            #pragma unroll
            for (int nt = 0; nt < 2; ++nt) {
                const int np = nt * 16 + m;
                #pragma unroll
                for (int rr = 0; rr < 4; ++rr)
                    epi[ft2 * 16 + q * 4 + rr][np] = acc[ft][nt][rr];
            }
        }
        #pragma unroll
        for (int inst = 0; inst < 4; ++inst) {
            const int fl = inst * 8 + (lane >> 3);
            const int np = (lane & 7) * 4;
            float4 v = *reinterpret_cast<const float4*>(&epi[fl][np]);
            *reinterpret_cast<float4*>(ob + (size_t)(fc * 32 + fl) * Nd + np) = v;
        }
    }
}

// ---- fallback fp32 kernel (ws too small) ----
__global__ __launch_bounds__(256, 4)
void swconv_f32_kernel(const float* __restrict__ x,
                       const float* __restrict__ coords,
                       const float* __restrict__ weight,
                       const void*  __restrict__ sigma_p,
                       float* __restrict__ out)
{
    __shared__ float xsf[Cd][NROWS + 1];
    __shared__ float csf[3][NROWS + 1];
    const int tid = threadIdx.x;
    const int tile = blockIdx.x, t = blockIdx.y, b = blockIdx.z;
    const int n0 = tile * NT;
    const float inv_sigma = 1.0f / sigma_as_float(sigma_p);

    const float* xbt = x + (size_t)(b * Td + t) * Cd * Nd;
    for (int idx = tid; idx < Cd * NROWS; idx += 256) {
        int c = idx / NROWS, i = idx - c * NROWS, n = n0 - PADd + i;
        xsf[c][i] = (n >= 0 && n < Nd) ? xbt[(size_t)c * Nd + n] : 0.0f;
    }
    const float* cbt = coords + (size_t)(b * Td + t) * 3 * Nd;
    for (int idx = tid; idx < 3 * NROWS; idx += 256) {
        int c = idx / NROWS, i = idx - c * NROWS, n = n0 - PADd + i;
        csf[c][i] = (n >= 0 && n < Nd) ? cbt[(size_t)c * Nd + n] : 0.0f;
    }
    __syncthreads();
    if (tid >= NT) return;

    float wk[Kd];
    {
        const float c0 = csf[0][tid + PADd], c1 = csf[1][tid + PADd], c2 = csf[2][tid + PADd];
        #pragma unroll
        for (int k = 0; k < Kd; ++k) {
            float d0 = csf[0][tid + k] - c0, d1 = csf[1][tid + k] - c1, d2 = csf[2][tid + k] - c2;
            float s = d0 * d0 + d1 * d1 + d2 * d2;
            float d = (s > 0.0f) ? sqrtf(s) : 0.0f;
            wk[k] = fmaxf(1.0f - d * inv_sigma, 0.0f);
        }
    }
    float accf[Fd];
    #pragma unroll
    for (int f = 0; f < Fd; ++f) accf[f] = 0.0f;
    const float* wt = weight + (size_t)t * Fd * Cd * Kd;
    for (int c = 0; c < Cd; ++c) {
        float xv[Kd];
        #pragma unroll
        for (int k = 0; k < Kd; ++k) xv[k] = xsf[c][tid + k];
        const float* wp = wt + c * Kd;
        #pragma unroll
        for (int k = 0; k < Kd; ++k) {
            float v = xv[k] * wk[k];
            #pragma unroll
            for (int f = 0; f < Fd; ++f)
                accf[f] = fmaf(v, wp[(size_t)f * Cd * Kd + k], accf[f]);
        }
    }
    float* op = out + (size_t)(b * Td + t) * Fd * Nd + n0 + tid;
    #pragma unroll
    for (int f = 0; f < Fd; ++f) op[(size_t)f * Nd] = accf[f];
}

extern "C" void kernel_launch(void* const* d_in, const int* in_sizes, int n_in,
                              void* d_out, int out_size, void* d_ws, size_t ws_size,
                              hipStream_t stream) {
    const float* x      = (const float*)d_in[0];
    const float* coords = (const float*)d_in[1];
    const float* weight = (const float*)d_in[2];
    const void*  sigma  = d_in[3];
    float* out = (float*)d_out;

    if (ws_size >= A_WS_BYTES) {
        unsigned short* aw = (unsigned short*)d_ws;
        prep_weights<<<(Td * Kd * 4 * 64 * 8 + 255) / 256, 256, 0, stream>>>(weight, aw);
        dim3 grid(Nd / NT, Td, Bd);   // 2048 blocks
        swconv_mfma4<<<grid, dim3(256), 0, stream>>>(x, coords, aw, sigma, out);
    } else {
        dim3 grid(Nd / NT, Td, Bd);
        swconv_f32_kernel<<<grid, dim3(256), 0, stream>>>(x, coords, weight, sigma, out);
    }
}